// Round 8
// baseline (178.986 us; speedup 1.0000x reference)
//
#include <hip/hip_runtime.h>
#include <hip/hip_cooperative_groups.h>
#include <hip/hip_bf16.h>

namespace cg = cooperative_groups;

#define H 768
#define K2P 1600          // 768 + 768 + 64 (width 30 padded to 64)
#define SEQLEN 512
#define NSPAN 128
#define NB 256            // grid size = 1 block per CU (co-residency guaranteed)

typedef __attribute__((ext_vector_type(8))) short s16x8;
typedef __attribute__((ext_vector_type(4))) float f32x4;

#define MFMA_BF16 __builtin_amdgcn_mfma_f32_16x16x32_bf16

__device__ __forceinline__ short f2bf(float f) {
    __hip_bfloat16 h = __float2bfloat16(f);
    return *reinterpret_cast<short*>(&h);
}
__device__ __forceinline__ float bf2f(short s) {
    unsigned int u = ((unsigned int)(unsigned short)s) << 16;
    return __builtin_bit_cast(float, u);
}

// Shared-memory union across phases (32 KB)
union SMem {
    struct { float t[2][32][33]; } tr;                         // transposes
    short gemm[2][8192];                                       // 2 x 16KB GEMM dbuf
    struct { float Ais[16][68], Bjs[16][68], w2s[768]; } pr;   // pair phase
};

// ---------------------------------------------------------------------------
// 64x64 GEMM tile, 256 threads (4 waves, one 32x32 quadrant each), BK=64.
// Round-7's proven race-free reg-staged double-buffer pipeline (only
// __syncthreads + data deps; no manual vmcnt). LDS buffer: A rows 0..63 at
// bytes [0,8192), B rows 0..63 at [8192,16384); row = 128B; XOR swizzle
// (slot ^ row&7) keeps stride-128B ds_read_b128 conflict-free (T2/G4).
// ---------------------------------------------------------------------------
#define SLOAD4(P, K0)                                                          \
    P##0 = *(const s16x8*)(gA0 + (K0));                                        \
    P##1 = *(const s16x8*)(gA1 + (K0));                                        \
    P##2 = *(const s16x8*)(gB0 + (K0));                                        \
    P##3 = *(const s16x8*)(gB1 + (K0));

#define SWRITE4(P, BUF)                                                        \
    *(s16x8*)((BUF) + dA0) = P##0;                                             \
    *(s16x8*)((BUF) + dA1) = P##1;                                             \
    *(s16x8*)((BUF) + dB0) = P##2;                                             \
    *(s16x8*)((BUF) + dB1) = P##3;

__device__ __forceinline__ void mstep64(const char* buf, int qr, int qc,
                                        int r, int hi,
                                        f32x4& a00, f32x4& a01,
                                        f32x4& a10, f32x4& a11)
{
    #pragma unroll
    for (int kc = 0; kc < 2; ++kc) {
        const int ko = kc*64 + hi*16;
        const int ra0 = qr + r, ra1 = qr + 16 + r;
        const int rb0 = qc + r, rb1 = qc + 16 + r;
        s16x8 av0 = *(const s16x8*)(buf + ra0*128 + (ko ^ ((ra0 & 7) << 4)));
        s16x8 av1 = *(const s16x8*)(buf + ra1*128 + (ko ^ ((ra1 & 7) << 4)));
        s16x8 bv0 = *(const s16x8*)(buf + 8192 + rb0*128 + (ko ^ ((rb0 & 7) << 4)));
        s16x8 bv1 = *(const s16x8*)(buf + 8192 + rb1*128 + (ko ^ ((rb1 & 7) << 4)));
        a00 = MFMA_BF16(av0, bv0, a00, 0, 0, 0);
        a01 = MFMA_BF16(av0, bv1, a01, 0, 0, 0);
        a10 = MFMA_BF16(av1, bv0, a10, 0, 0, 0);
        a11 = MFMA_BF16(av1, bv1, a11, 0, 0, 0);
    }
}

__device__ __forceinline__ void gemm64(
    short* ldsbase,
    const short* __restrict__ A, int ldA, int am0,
    const short* __restrict__ Wt, int ldW, int n0,
    int nsteps, int tid,
    f32x4& a00, f32x4& a01, f32x4& a10, f32x4& a11)
{
    const int w = tid >> 6, l = tid & 63;
    const int qr = (w >> 1) * 32, qc = (w & 1) * 32;
    const int r = l & 15, hi = l >> 4;

    const int rowA0 = tid >> 3, rowA1 = rowA0 + 32, sl = tid & 7;
    const short* gA0 = A + (size_t)(am0 + rowA0) * ldA + ((sl ^ (rowA0 & 7)) << 3);
    const short* gA1 = A + (size_t)(am0 + rowA1) * ldA + ((sl ^ (rowA1 & 7)) << 3);
    const short* gB0 = Wt + (size_t)(n0 + rowA0) * ldW + ((sl ^ (rowA0 & 7)) << 3);
    const short* gB1 = Wt + (size_t)(n0 + rowA1) * ldW + ((sl ^ (rowA1 & 7)) << 3);
    const int dA0 = rowA0*128 + sl*16, dA1 = dA0 + 4096;
    const int dB0 = 8192 + rowA0*128 + sl*16, dB1 = dB0 + 4096;
    char* b0 = (char*)ldsbase;
    char* b1 = (char*)ldsbase + 16384;

    s16x8 Pa0, Pa1, Pa2, Pa3;
    s16x8 Pb0, Pb1, Pb2, Pb3;

    SLOAD4(Pa, 0)
    SWRITE4(Pa, b0)
    SLOAD4(Pa, 64)
    __syncthreads();
    for (int s = 0; s < nsteps; s += 2) {
        if (s + 2 < nsteps) { SLOAD4(Pb, 64*(s+2)) }
        mstep64(b0, qr, qc, r, hi, a00, a01, a10, a11);
        if (s + 1 < nsteps) { SWRITE4(Pa, b1) }
        __syncthreads();
        if (s + 1 < nsteps) {
            if (s + 3 < nsteps) { SLOAD4(Pa, 64*(s+3)) }
            mstep64(b1, qr, qc, r, hi, a00, a01, a10, a11);
            if (s + 2 < nsteps) { SWRITE4(Pb, b0) }
            __syncthreads();
        }
    }
}

// ---------------------------------------------------------------------------
// The cooperative mega-kernel: prep -> g1 -> g2 -> g3+mention -> pair,
// separated by grid.sync(). 256 blocks x 256 threads.
// ---------------------------------------------------------------------------
__global__ __launch_bounds__(256) void k_mega(
    const float* __restrict__ seq,
    const int* __restrict__ starts, const int* __restrict__ ends,
    const float* __restrict__ Ws, const float* __restrict__ bs,
    const float* __restrict__ We, const float* __restrict__ be,
    const float* __restrict__ wemb,
    const float* __restrict__ Wout, const float* __restrict__ bout,
    const float* __restrict__ Wm, const float* __restrict__ bment,
    const float* __restrict__ W1, const float* __restrict__ b1,
    const float* __restrict__ W2, const float* __restrict__ b2,
    short* __restrict__ WtSE, short* __restrict__ WtAB,
    short* __restrict__ WtOut, short* __restrict__ Xg,
    short* __restrict__ Xcat, short* __restrict__ SR,
    float* __restrict__ AB, float* __restrict__ mention,
    float* __restrict__ pair)
{
    __shared__ __align__(16) SMem sm;
    const int tid = threadIdx.x;
    const int bid = blockIdx.x;
    cg::grid_group grid = cg::this_grid();

    // ======== Phase 0: weight transposes (3504 tiles), gather, width cols ===
    {
        auto load_tr = [&](int t) -> float4 {
            const int kk = tid >> 3, c4 = (tid & 7) << 2;
            if (t < 2304) {
                const int sec = t / 576, tt = t % 576;
                const int kt = tt / 24, nt = tt % 24;
                const int srow = kt*32 + kk, scol = nt*32 + c4;
                if (sec == 0) return *(const float4*)(Ws + (size_t)srow * H + scol);
                if (sec == 1) return *(const float4*)(We + (size_t)srow * H + scol);
                const float* base = W1 + (size_t)(sec == 2 ? 0 : H) * H;
                float4 u = *(const float4*)(base + (size_t)srow * H + scol);
                float4 c = *(const float4*)(W1 + (size_t)2*H*H + (size_t)srow * H + scol);
                const float sg = (sec == 2) ? 1.f : -1.f;
                return make_float4(fmaf(sg,c.x,u.x), fmaf(sg,c.y,u.y),
                                   fmaf(sg,c.z,u.z), fmaf(sg,c.w,u.w));
            } else {
                const int tt = t - 2304;
                const int nt = tt / 50, kt = tt % 50;
                const int srow = kt*32 + kk, scol = nt*32 + c4;
                if (srow < 1566) return *(const float4*)(Wout + (size_t)srow * H + scol);
                return make_float4(0.f, 0.f, 0.f, 0.f);
            }
        };

        int t = bid;   // bid < 256 < 3504 always: every block does >= 13 tiles
        float4 v = load_tr(t);
        int pb = 0;
        while (true) {
            const int kk = tid >> 3, c4 = (tid & 7) << 2;
            sm.tr.t[pb][kk][c4+0] = v.x; sm.tr.t[pb][kk][c4+1] = v.y;
            sm.tr.t[pb][kk][c4+2] = v.z; sm.tr.t[pb][kk][c4+3] = v.w;
            const int tn = t + NB;
            float4 vn;
            if (tn < 3504) vn = load_tr(tn);      // prefetch next tile
            __syncthreads();
            {   // transpose-store from LDS
                const int nn = tid >> 3;
                short4 o;
                o.x = f2bf(sm.tr.t[pb][c4+0][nn]); o.y = f2bf(sm.tr.t[pb][c4+1][nn]);
                o.z = f2bf(sm.tr.t[pb][c4+2][nn]); o.w = f2bf(sm.tr.t[pb][c4+3][nn]);
                if (t < 2304) {
                    const int sec = t / 576, tt = t % 576;
                    const int kt = tt / 24, nt = tt % 24;
                    short* dst = (sec < 2 ? WtSE : WtAB) + (size_t)(sec & 1) * H * H;
                    *(short4*)(dst + (size_t)(nt*32 + nn) * H + kt*32 + c4) = o;
                } else {
                    const int tt = t - 2304;
                    const int nt = tt / 50, kt = tt % 50;
                    *(short4*)(WtOut + (size_t)(nt*32 + nn) * K2P + kt*32 + c4) = o;
                }
            }
            if (tn >= 3504) break;
            v = vn; t = tn; pb ^= 1;
        }

        // gather: Xg rows [0,512)=starts, [512,1024)=ends ; 4 rows per block
        {
            const int gr = bid*4 + (tid >> 6), c = tid & 63;
            const int spanrow = gr & 511;
            const int idx = (gr < 512) ? starts[spanrow] : ends[spanrow];
            const float* src = seq + ((size_t)(spanrow >> 7) * SEQLEN + idx) * H;
            short* dst = Xg + (size_t)gr * H;
            #pragma unroll
            for (int i = 0; i < 12; ++i)
                dst[c + i*64] = f2bf(src[c + i*64]);
        }
        // width-emb cols 1536..1599 of Xcat ; 2 rows per block
        if (tid < 128) {
            const int row = bid*2 + (tid >> 6), c = tid & 63;
            int wd = ends[row] - starts[row];
            wd = wd < 0 ? 0 : (wd > 10 ? 10 : wd);
            Xcat[(size_t)row * K2P + 1536 + c] = (c < 30) ? f2bf(wemb[wd*30 + c]) : (short)0;
        }
    }
    grid.sync();

    // ======== Phase 1: g1 — Xcat[:,0:1536] = Xg @ WtSE^T + bias (192 jobs) ==
    if (bid < 192) {
        const int bm = bid / 24, bn = bid % 24;
        const int n0 = bn * 64;
        const int am0 = (n0 >= 768 ? 512 : 0) + bm * 64;
        f32x4 a00 = {}, a01 = {}, a10 = {}, a11 = {};
        gemm64(&sm.gemm[0][0], Xg, H, am0, WtSE, H, n0, 12, tid, a00, a01, a10, a11);

        const int w = tid >> 6, l = tid & 63;
        const int qr = (w >> 1) * 32, qc = (w & 1) * 32;
        const int r = l & 15, hi = l >> 4;
        const int gc0 = n0 + qc + r, gc1 = gc0 + 16;
        const float bv0 = (gc0 < 768) ? bs[gc0] : be[gc0 - 768];
        const float bv1 = (gc1 < 768) ? bs[gc1] : be[gc1 - 768];
        const int r0 = bm*64 + qr + hi*4, r1 = r0 + 16;
        #pragma unroll
        for (int rg = 0; rg < 4; ++rg) {
            Xcat[(size_t)(r0 + rg) * K2P + gc0] = f2bf(a00[rg] + bv0);
            Xcat[(size_t)(r0 + rg) * K2P + gc1] = f2bf(a01[rg] + bv1);
            Xcat[(size_t)(r1 + rg) * K2P + gc0] = f2bf(a10[rg] + bv0);
            Xcat[(size_t)(r1 + rg) * K2P + gc1] = f2bf(a11[rg] + bv1);
        }
    }
    grid.sync();

    // ======== Phase 2: g2 — SR = Xcat(K=1600) @ WtOut^T + b_out (96 jobs) ===
    if (bid < 96) {
        const int bm = bid / 12, bn = bid % 12;
        const int n0 = bn * 64;
        f32x4 a00 = {}, a01 = {}, a10 = {}, a11 = {};
        gemm64(&sm.gemm[0][0], Xcat, K2P, bm*64, WtOut, K2P, n0, 25, tid, a00, a01, a10, a11);

        const int w = tid >> 6, l = tid & 63;
        const int qr = (w >> 1) * 32, qc = (w & 1) * 32;
        const int r = l & 15, hi = l >> 4;
        const int gc0 = n0 + qc + r, gc1 = gc0 + 16;
        const float bv0 = bout[gc0], bv1 = bout[gc1];
        const int r0 = bm*64 + qr + hi*4, r1 = r0 + 16;
        #pragma unroll
        for (int rg = 0; rg < 4; ++rg) {
            SR[(size_t)(r0 + rg) * H + gc0] = f2bf(a00[rg] + bv0);
            SR[(size_t)(r0 + rg) * H + gc1] = f2bf(a01[rg] + bv1);
            SR[(size_t)(r1 + rg) * H + gc0] = f2bf(a10[rg] + bv0);
            SR[(size_t)(r1 + rg) * H + gc1] = f2bf(a11[rg] + bv1);
        }
    }
    grid.sync();

    // ======== Phase 3: g3 (192 jobs) + mention (blocks 192..255) ============
    if (bid < 192) {
        const int bm = bid / 24, bn = bid % 24;
        const int n0 = bn * 64;
        f32x4 a00 = {}, a01 = {}, a10 = {}, a11 = {};
        gemm64(&sm.gemm[0][0], SR, H, bm*64, WtAB, H, n0, 12, tid, a00, a01, a10, a11);

        const int w = tid >> 6, l = tid & 63;
        const int qr = (w >> 1) * 32, qc = (w & 1) * 32;
        const int r = l & 15, hi = l >> 4;
        const int gc0 = n0 + qc + r, gc1 = gc0 + 16;
        const float bv0 = (gc0 < 768) ? b1[gc0] : 0.f;
        const float bv1 = (gc1 < 768) ? b1[gc1] : 0.f;
        const int r0 = bm*64 + qr + hi*4, r1 = r0 + 16;
        #pragma unroll
        for (int rg = 0; rg < 4; ++rg) {
            AB[(size_t)(r0 + rg) * 1536 + gc0] = a00[rg] + bv0;
            AB[(size_t)(r0 + rg) * 1536 + gc1] = a01[rg] + bv1;
            AB[(size_t)(r1 + rg) * 1536 + gc0] = a10[rg] + bv0;
            AB[(size_t)(r1 + rg) * 1536 + gc1] = a11[rg] + bv1;
        }
    } else {
        // mention = SR @ Wm + b_ment ; 64 blocks x 8 rows (4 waves x 2 rows)
        const int w = tid >> 6, l = tid & 63;
        const float bm_add = bment[0];
        #pragma unroll
        for (int rr = 0; rr < 2; ++rr) {
            const int row = (bid - 192)*8 + w*2 + rr;
            float p = 0.f;
            #pragma unroll
            for (int kk = 0; kk < 12; ++kk) {
                const int k = kk*64 + l;
                p = fmaf(bf2f(SR[(size_t)row * H + k]), Wm[k], p);
            }
            #pragma unroll
            for (int off = 32; off; off >>= 1) p += __shfl_down(p, off);
            if (l == 0) mention[row] = p + bm_add;
        }
    }
    grid.sync();

    // ======== Phase 4: pair (256 jobs, one per block) ========================
    {
        const int bz = bid >> 6, tt = bid & 63;
        const int bx = tt & 7, by = tt >> 3;
        const int tx = tid & 15, ty = tid >> 4;
        const int i = by*16 + ty, j = bx*16 + tx;
        float* outp = pair + ((size_t)bz * NSPAN + i) * NSPAN + j;

        if (bx > by) { *outp = 0.f; return; }   // strictly-upper: zeros

        for (int q = tid; q < 768; q += 256) sm.pr.w2s[q] = W2[q];

        const int sr = tid >> 4, sc = (tid & 15) << 2;
        const float* aSrc = AB + ((size_t)bz*NSPAN + by*16 + sr)*1536 + sc;
        const float* bSrc = AB + ((size_t)bz*NSPAN + bx*16 + sr)*1536 + 768 + sc;
        float acc = 0.f;

        float4 ra = *(const float4*)(aSrc);
        float4 rb = *(const float4*)(bSrc);

        for (int ch = 0; ch < 12; ++ch) {
            __syncthreads();
            *(float4*)&sm.pr.Ais[sr][sc] = ra;
            *(float4*)&sm.pr.Bjs[sr][sc] = rb;
            __syncthreads();
            if (ch < 11) {
                ra = *(const float4*)(aSrc + (ch+1)*64);
                rb = *(const float4*)(bSrc + (ch+1)*64);
            }
            #pragma unroll
            for (int hq = 0; hq < 16; ++hq) {
                float4 a = *(const float4*)&sm.pr.Ais[ty][hq << 2];
                float4 b = *(const float4*)&sm.pr.Bjs[tx][hq << 2];
                float4 wv = *(const float4*)&sm.pr.w2s[ch*64 + (hq << 2)];
                acc = fmaf(fmaxf(a.x + b.x, 0.f), wv.x, acc);
                acc = fmaf(fmaxf(a.y + b.y, 0.f), wv.y, acc);
                acc = fmaf(fmaxf(a.z + b.z, 0.f), wv.z, acc);
                acc = fmaf(fmaxf(a.w + b.w, 0.f), wv.w, acc);
            }
        }
        *outp = (j < i) ? (acc + b2[0]) : 0.f;
    }
}

// ---------------------------------------------------------------------------
extern "C" void kernel_launch(void* const* d_in, const int* in_sizes, int n_in,
                              void* d_out, int out_size, void* d_ws, size_t ws_size,
                              hipStream_t stream)
{
    const float* seq    = (const float*)d_in[0];
    const int*   starts = (const int*)  d_in[1];
    const int*   ends   = (const int*)  d_in[2];
    const float* Ws     = (const float*)d_in[3];
    const float* bs     = (const float*)d_in[4];
    const float* We     = (const float*)d_in[5];
    const float* be     = (const float*)d_in[6];
    const float* wemb   = (const float*)d_in[7];
    const float* Wout   = (const float*)d_in[8];
    const float* bout   = (const float*)d_in[9];
    const float* Wm     = (const float*)d_in[10];
    const float* bment  = (const float*)d_in[11];
    const float* W1     = (const float*)d_in[12];
    const float* b1     = (const float*)d_in[13];
    const float* W2     = (const float*)d_in[14];
    const float* b2     = (const float*)d_in[15];

    float* ws = (float*)d_ws;
    float* AB    = ws;                          // 512*1536 fp32
    short* Xg    = (short*)(ws + 786432);       // 1024*768 bf16
    short* Xcat  = (short*)(ws + 1179648);      // 512*1600 bf16
    short* SR    = (short*)(ws + 1589248);      // 512*768  bf16
    short* WtSE  = (short*)(ws + 1785856);      // 1536*768 bf16
    short* WtAB  = (short*)(ws + 2375680);      // 1536*768 bf16
    short* WtOut = (short*)(ws + 2965504);      // 768*1600 bf16

    float* out_mention = (float*)d_out;         // 512
    float* out_pair    = (float*)d_out + 512;   // 4*128*128

    void* args[] = {
        (void*)&seq, (void*)&starts, (void*)&ends,
        (void*)&Ws, (void*)&bs, (void*)&We, (void*)&be, (void*)&wemb,
        (void*)&Wout, (void*)&bout, (void*)&Wm, (void*)&bment,
        (void*)&W1, (void*)&b1, (void*)&W2, (void*)&b2,
        (void*)&WtSE, (void*)&WtAB, (void*)&WtOut, (void*)&Xg,
        (void*)&Xcat, (void*)&SR, (void*)&AB,
        (void*)&out_mention, (void*)&out_pair
    };
    hipLaunchCooperativeKernel((const void*)k_mega, dim3(NB), dim3(256),
                               args, 0, stream);
}

// Round 9
// 46.898 us; speedup vs baseline: 3.8165x; 3.8165x over previous
//
#include <hip/hip_runtime.h>
#include <hip/hip_bf16.h>

#define H 768
#define K2P 1600          // 768 + 768 + 64 (width 30 padded to 64)
#define SEQLEN 512
#define NSPAN 128

typedef __attribute__((ext_vector_type(8))) short s16x8;
typedef __attribute__((ext_vector_type(4))) float f32x4;

#define MFMA_BF16 __builtin_amdgcn_mfma_f32_16x16x32_bf16

__device__ __forceinline__ short f2bf(float f) {
    __hip_bfloat16 h = __float2bfloat16(f);
    return *reinterpret_cast<short*>(&h);
}
__device__ __forceinline__ float bf2f(short s) {
    unsigned int u = ((unsigned int)(unsigned short)s) << 16;
    return __builtin_bit_cast(float, u);
}

// ---------------------------------------------------------------------------
// 32x32 GEMM tile, 128 threads (2 waves; wave w owns cols w*16..+15), BK=64.
// Round-7's proven race-free reg-staged double-buffer pipeline: only
// __syncthreads + compiler-tracked data deps (no manual vmcnt — r5 lesson).
// LDS buffer (8 KB): A rows 0..31 at [0,4096), B rows 0..31 at [4096,8192);
// row = 128B; XOR swizzle (slot ^ row&7) keeps ds_read_b128 conflict-free.
// Staging: 4x16B global loads/thread -> regs (1 step early) -> ds_write.
// ---------------------------------------------------------------------------
#define SLOAD(P, K0)                                                           \
    P##0 = *(const s16x8*)(gA0 + (K0));                                        \
    P##1 = *(const s16x8*)(gA1 + (K0));                                        \
    P##2 = *(const s16x8*)(gB0 + (K0));                                        \
    P##3 = *(const s16x8*)(gB1 + (K0));

#define SWRITE(P, BUF)                                                         \
    *(s16x8*)((BUF) + dA0) = P##0;                                             \
    *(s16x8*)((BUF) + dA1) = P##1;                                             \
    *(s16x8*)((BUF) + dB0) = P##2;                                             \
    *(s16x8*)((BUF) + dB1) = P##3;

__device__ __forceinline__ void mstep32(const char* buf, int w, int r, int hi,
                                        f32x4& a0, f32x4& a1)
{
    #pragma unroll
    for (int kc = 0; kc < 2; ++kc) {
        const int ko = kc*64 + hi*16;
        const int ra0 = r, ra1 = 16 + r, rb = w*16 + r;
        s16x8 av0 = *(const s16x8*)(buf + ra0*128 + (ko ^ ((ra0 & 7) << 4)));
        s16x8 av1 = *(const s16x8*)(buf + ra1*128 + (ko ^ ((ra1 & 7) << 4)));
        s16x8 bv  = *(const s16x8*)(buf + 4096 + rb*128 + (ko ^ ((rb & 7) << 4)));
        a0 = MFMA_BF16(av0, bv, a0, 0, 0, 0);
        a1 = MFMA_BF16(av1, bv, a1, 0, 0, 0);
    }
}

__device__ __forceinline__ void gemm3232(
    short* ldsb,                       // 2 x 8192 bytes
    const short* __restrict__ A, int ldA, int am0,
    const short* __restrict__ Wt, int ldW, int n0,
    int nsteps, int tid,
    f32x4& a0, f32x4& a1)
{
    const int w = tid >> 6, l = tid & 63;
    const int r = l & 15, hi = l >> 4;

    const int rr = tid >> 3, sl = tid & 7;   // rr 0..15, 16B slot sl
    const short* gA0 = A + (size_t)(am0 + rr) * ldA + ((sl ^ (rr & 7)) << 3);
    const short* gA1 = A + (size_t)(am0 + rr + 16) * ldA + ((sl ^ (rr & 7)) << 3);
    const short* gB0 = Wt + (size_t)(n0 + rr) * ldW + ((sl ^ (rr & 7)) << 3);
    const short* gB1 = Wt + (size_t)(n0 + rr + 16) * ldW + ((sl ^ (rr & 7)) << 3);
    const int dA0 = rr*128 + sl*16,        dA1 = (rr+16)*128 + sl*16;
    const int dB0 = 4096 + rr*128 + sl*16, dB1 = 4096 + (rr+16)*128 + sl*16;
    char* b0 = (char*)ldsb;
    char* b1 = (char*)ldsb + 8192;

    s16x8 Pa0, Pa1, Pa2, Pa3;
    s16x8 Pb0, Pb1, Pb2, Pb3;

    SLOAD(Pa, 0)
    SWRITE(Pa, b0)
    SLOAD(Pa, 64)
    __syncthreads();
    for (int s = 0; s < nsteps; s += 2) {
        if (s + 2 < nsteps) { SLOAD(Pb, 64*(s+2)) }
        mstep32(b0, w, r, hi, a0, a1);
        if (s + 1 < nsteps) { SWRITE(Pa, b1) }
        __syncthreads();
        if (s + 1 < nsteps) {
            if (s + 3 < nsteps) { SLOAD(Pa, 64*(s+3)) }
            mstep32(b1, w, r, hi, a0, a1);
            if (s + 2 < nsteps) { SWRITE(Pb, b0) }
            __syncthreads();
        }
    }
}

// ---------------------------------------------------------------------------
// P0: weight transposes -> bf16 [n][k]; gather seq -> Xg bf16; Xcat width cols.
// ---------------------------------------------------------------------------
__global__ __launch_bounds__(256) void k_prep(
    const float* __restrict__ seq,
    const int* __restrict__ starts, const int* __restrict__ ends,
    const float* __restrict__ Ws, const float* __restrict__ We,
    const float* __restrict__ W1, const float* __restrict__ Wout,
    const float* __restrict__ wemb,
    short* __restrict__ WtSE, short* __restrict__ WtAB,
    short* __restrict__ WtOut, short* __restrict__ Xg, short* __restrict__ Xcat)
{
    const int b = blockIdx.x;
    const int tid = threadIdx.x;

    if (b < 2304) {                       // Ws/We/Wa+Wc/Wb-Wc transposes
        const int sec = b / 576;
        const int t = b % 576;
        const int kt = t / 24, nt = t % 24;
        __shared__ float tile[32][33];
        const int kk = tid >> 3;
        const int c4 = (tid & 7) << 2;
        const int srow = kt * 32 + kk, scol = nt * 32 + c4;
        float4 v;
        if (sec == 0)      v = *(const float4*)(Ws + (size_t)srow * H + scol);
        else if (sec == 1) v = *(const float4*)(We + (size_t)srow * H + scol);
        else {
            const float* base = W1 + (size_t)(sec == 2 ? 0 : H) * H;
            float4 u = *(const float4*)(base + (size_t)srow * H + scol);
            float4 c = *(const float4*)(W1 + (size_t)2*H*H + (size_t)srow * H + scol);
            const float sg = (sec == 2) ? 1.f : -1.f;
            v = make_float4(fmaf(sg,c.x,u.x), fmaf(sg,c.y,u.y),
                            fmaf(sg,c.z,u.z), fmaf(sg,c.w,u.w));
        }
        tile[kk][c4+0]=v.x; tile[kk][c4+1]=v.y; tile[kk][c4+2]=v.z; tile[kk][c4+3]=v.w;
        __syncthreads();
        short* dst = (sec < 2 ? WtSE : WtAB) + (size_t)(sec & 1) * H * H;
        const int nn = tid >> 3;
        short4 o;
        o.x = f2bf(tile[c4+0][nn]); o.y = f2bf(tile[c4+1][nn]);
        o.z = f2bf(tile[c4+2][nn]); o.w = f2bf(tile[c4+3][nn]);
        *(short4*)(dst + (size_t)(nt*32 + nn) * H + kt*32 + c4) = o;
    } else if (b < 3504) {                // Wout^T -> [768][1600], zero-padded
        const int t = b - 2304;
        const int nt = t / 50, kt = t % 50;
        __shared__ float tile[32][33];
        const int kk = tid >> 3;
        const int c4 = (tid & 7) << 2;
        const int srow = kt * 32 + kk, scol = nt * 32 + c4;
        float4 v = make_float4(0.f, 0.f, 0.f, 0.f);
        if (srow < 1566) v = *(const float4*)(Wout + (size_t)srow * H + scol);
        tile[kk][c4+0]=v.x; tile[kk][c4+1]=v.y; tile[kk][c4+2]=v.z; tile[kk][c4+3]=v.w;
        __syncthreads();
        const int nn = tid >> 3;
        short4 o;
        o.x = f2bf(tile[c4+0][nn]); o.y = f2bf(tile[c4+1][nn]);
        o.z = f2bf(tile[c4+2][nn]); o.w = f2bf(tile[c4+3][nn]);
        *(short4*)(WtOut + (size_t)(nt*32 + nn) * K2P + kt*32 + c4) = o;
    } else if (b < 3760) {                // gather: Xg[0:512)=starts, [512:1024)=ends
        const int gr = (b - 3504) * 4 + (tid >> 6);
        const int c = tid & 63;
        const int spanrow = gr & 511;
        const int idx = (gr < 512) ? starts[spanrow] : ends[spanrow];
        const size_t base = ((size_t)(spanrow >> 7) * SEQLEN + idx) * H;
        #pragma unroll
        for (int i = 0; i < 12; ++i) {
            const int col = c + i*64;
            Xg[(size_t)gr * H + col] = f2bf(seq[base + col]);
        }
    } else {                              // Xcat width-emb cols 1536..1599
        const int t = (b - 3760) * 256 + tid;
        const int row = t >> 6, c = t & 63;
        int wd = ends[row] - starts[row];
        wd = wd < 0 ? 0 : (wd > 10 ? 10 : wd);
        Xcat[(size_t)row * K2P + 1536 + c] = (c < 30) ? f2bf(wemb[wd*30 + c]) : (short)0;
    }
}

// ---------------------------------------------------------------------------
// G1: Xcat[:, gc] = Xg(half) @ WtSE^T + bias   (N = 1536, 48 col-tiles of 32)
// ---------------------------------------------------------------------------
__global__ __launch_bounds__(128) void k_g1(
    const short* __restrict__ Xg, const short* __restrict__ WtSE,
    const float* __restrict__ bs, const float* __restrict__ be,
    short* __restrict__ Xcat)
{
    __shared__ __align__(16) short lds[2][4096];
    const int tid = threadIdx.x;
    const int bm = blockIdx.x, n0 = blockIdx.y * 32;
    const int am0 = (n0 >= 768 ? 512 : 0) + bm * 32;

    f32x4 a0 = {}, a1 = {};
    gemm3232(&lds[0][0], Xg, H, am0, WtSE, H, n0, 12, tid, a0, a1);

    const int w = tid >> 6, l = tid & 63;
    const int r = l & 15, hi = l >> 4;
    const int gc = n0 + w*16 + r;
    const float bv = (gc < 768) ? bs[gc] : be[gc - 768];
    const int r0 = bm*32 + hi*4, r1 = r0 + 16;
    #pragma unroll
    for (int rg = 0; rg < 4; ++rg) {
        Xcat[(size_t)(r0 + rg) * K2P + gc] = f2bf(a0[rg] + bv);
        Xcat[(size_t)(r1 + rg) * K2P + gc] = f2bf(a1[rg] + bv);
    }
}

// ---------------------------------------------------------------------------
// G2: SR = Xcat(K=1600) @ WtOut^T + b_out   (24 col-tiles of 32)
// ---------------------------------------------------------------------------
__global__ __launch_bounds__(128) void k_g2(
    const short* __restrict__ Xcat, const short* __restrict__ WtOut,
    const float* __restrict__ bout, short* __restrict__ SR)
{
    __shared__ __align__(16) short lds[2][4096];
    const int tid = threadIdx.x;
    const int bm = blockIdx.x, n0 = blockIdx.y * 32;

    f32x4 a0 = {}, a1 = {};
    gemm3232(&lds[0][0], Xcat, K2P, bm*32, WtOut, K2P, n0, 25, tid, a0, a1);

    const int w = tid >> 6, l = tid & 63;
    const int r = l & 15, hi = l >> 4;
    const int gc = n0 + w*16 + r;
    const float bv = bout[gc];
    const int r0 = bm*32 + hi*4, r1 = r0 + 16;
    #pragma unroll
    for (int rg = 0; rg < 4; ++rg) {
        SR[(size_t)(r0 + rg) * H + gc] = f2bf(a0[rg] + bv);
        SR[(size_t)(r1 + rg) * H + gc] = f2bf(a1[rg] + bv);
    }
}

// ---------------------------------------------------------------------------
// G3: y<48: AB[:, gc] = SR @ WtAB^T (+b1 for cols<768)   [fp32 out]
//     y==48: mention = SR @ Wm + b_ment
// ---------------------------------------------------------------------------
__global__ __launch_bounds__(128) void k_g3(
    const short* __restrict__ SR, const short* __restrict__ WtAB,
    const float* __restrict__ b1, const float* __restrict__ Wm,
    const float* __restrict__ bment,
    float* __restrict__ AB, float* __restrict__ mention)
{
    const int tid = threadIdx.x;
    const int bm = blockIdx.x;

    if (blockIdx.y == 48) {               // mention scores, 32 rows per block
        const int w = tid >> 6, l = tid & 63;
        const int rows0 = bm*32 + w*16;
        const float bm_add = bment[0];
        for (int rr = 0; rr < 16; ++rr) {
            const int row = rows0 + rr;
            float p = 0.f;
            #pragma unroll
            for (int kk = 0; kk < 12; ++kk) {
                const int k = kk*64 + l;
                p = fmaf(bf2f(SR[(size_t)row * H + k]), Wm[k], p);
            }
            #pragma unroll
            for (int off = 32; off; off >>= 1) p += __shfl_down(p, off);
            if (l == 0) mention[row] = p + bm_add;
        }
        return;
    }

    __shared__ __align__(16) short lds[2][4096];
    const int n0 = blockIdx.y * 32;

    f32x4 a0 = {}, a1 = {};
    gemm3232(&lds[0][0], SR, H, bm*32, WtAB, H, n0, 12, tid, a0, a1);

    const int w = tid >> 6, l = tid & 63;
    const int r = l & 15, hi = l >> 4;
    const int gc = n0 + w*16 + r;
    const float bv = (gc < 768) ? b1[gc] : 0.f;
    const int r0 = bm*32 + hi*4, r1 = r0 + 16;
    #pragma unroll
    for (int rg = 0; rg < 4; ++rg) {
        AB[(size_t)(r0 + rg) * 1536 + gc] = a0[rg] + bv;
        AB[(size_t)(r1 + rg) * 1536 + gc] = a1[rg] + bv;
    }
}

// ---------------------------------------------------------------------------
// G4: pair[b,i,j] = (j<i) ? sum_h relu(AI+BJ)*W2[h] + b2 : 0
// Full 8x8 tile grid; upper tiles write zeros (no memset needed).
// Register-prefetch of next chunk overlaps global latency with compute.
// AB = [512][1536] fp32, AI at +0 (b1 folded), BJ at +768.
// ---------------------------------------------------------------------------
__global__ __launch_bounds__(256) void k_pair(
    const float* __restrict__ AB, const float* __restrict__ W2,
    const float* __restrict__ b2, float* __restrict__ pair)
{
    const int tid = threadIdx.x;
    const int bx = blockIdx.x & 7, by = blockIdx.x >> 3;
    const int bz = blockIdx.y;

    const int tx = tid & 15, ty = tid >> 4;
    const int i = by * 16 + ty, j = bx * 16 + tx;
    float* outp = pair + ((size_t)bz * NSPAN + i) * NSPAN + j;

    if (bx > by) { *outp = 0.f; return; }   // strictly-upper tile: all zero

    __shared__ __align__(16) float Ais[16][68];
    __shared__ __align__(16) float Bjs[16][68];
    __shared__ __align__(16) float w2s[768];
    for (int q = tid; q < 768; q += 256) w2s[q] = W2[q];

    const int sr = tid >> 4, sc = (tid & 15) << 2;
    const float* aSrc = AB + ((size_t)bz*NSPAN + by*16 + sr)*1536 + sc;
    const float* bSrc = AB + ((size_t)bz*NSPAN + bx*16 + sr)*1536 + 768 + sc;
    float acc = 0.f;

    float4 ra = *(const float4*)(aSrc);
    float4 rb = *(const float4*)(bSrc);

    for (int ch = 0; ch < 12; ++ch) {
        __syncthreads();
        *(float4*)&Ais[sr][sc] = ra;
        *(float4*)&Bjs[sr][sc] = rb;
        __syncthreads();
        if (ch < 11) {                       // next-chunk loads hide under FMAs
            ra = *(const float4*)(aSrc + (ch+1)*64);
            rb = *(const float4*)(bSrc + (ch+1)*64);
        }
        #pragma unroll
        for (int hq = 0; hq < 16; ++hq) {
            float4 a = *(const float4*)&Ais[ty][hq << 2];
            float4 b = *(const float4*)&Bjs[tx][hq << 2];
            float4 wv = *(const float4*)&w2s[ch*64 + (hq << 2)];
            acc = fmaf(fmaxf(a.x + b.x, 0.f), wv.x, acc);
            acc = fmaf(fmaxf(a.y + b.y, 0.f), wv.y, acc);
            acc = fmaf(fmaxf(a.z + b.z, 0.f), wv.z, acc);
            acc = fmaf(fmaxf(a.w + b.w, 0.f), wv.w, acc);
        }
    }
    *outp = (j < i) ? (acc + b2[0]) : 0.f;
}

// ---------------------------------------------------------------------------
extern "C" void kernel_launch(void* const* d_in, const int* in_sizes, int n_in,
                              void* d_out, int out_size, void* d_ws, size_t ws_size,
                              hipStream_t stream)
{
    const float* seq    = (const float*)d_in[0];
    const int*   starts = (const int*)  d_in[1];
    const int*   ends   = (const int*)  d_in[2];
    const float* Ws     = (const float*)d_in[3];
    const float* bs     = (const float*)d_in[4];
    const float* We     = (const float*)d_in[5];
    const float* be     = (const float*)d_in[6];
    const float* wemb   = (const float*)d_in[7];
    const float* Wout   = (const float*)d_in[8];
    const float* bout   = (const float*)d_in[9];
    const float* Wm     = (const float*)d_in[10];
    const float* bment  = (const float*)d_in[11];
    const float* W1     = (const float*)d_in[12];
    const float* b1     = (const float*)d_in[13];
    const float* W2     = (const float*)d_in[14];
    const float* b2     = (const float*)d_in[15];

    float* ws = (float*)d_ws;
    float* AB    = ws;                          // 512*1536 fp32
    short* Xg    = (short*)(ws + 786432);       // 1024*768 bf16
    short* Xcat  = (short*)(ws + 1179648);      // 512*1600 bf16
    short* SR    = (short*)(ws + 1589248);      // 512*768  bf16
    short* WtSE  = (short*)(ws + 1785856);      // 1536*768 bf16
    short* WtAB  = (short*)(ws + 2375680);      // 1536*768 bf16
    short* WtOut = (short*)(ws + 2965504);      // 768*1600 bf16

    float* out_mention = (float*)d_out;         // 512
    float* out_pair    = (float*)d_out + 512;   // 4*128*128

    hipLaunchKernelGGL(k_prep, dim3(3888), dim3(256), 0, stream,
                       seq, starts, ends, Ws, We, W1, Wout, wemb,
                       WtSE, WtAB, WtOut, Xg, Xcat);
    hipLaunchKernelGGL(k_g1, dim3(16, 48), dim3(128), 0, stream,
                       Xg, WtSE, bs, be, Xcat);
    hipLaunchKernelGGL(k_g2, dim3(16, 24), dim3(128), 0, stream,
                       Xcat, WtOut, bout, SR);
    hipLaunchKernelGGL(k_g3, dim3(16, 49), dim3(128), 0, stream,
                       SR, WtAB, b1, Wm, bment, AB, out_mention);
    hipLaunchKernelGGL(k_pair, dim3(64, 4), dim3(256), 0, stream,
                       AB, W2, b2, out_pair);
}